// Round 1
// baseline (439.998 us; speedup 1.0000x reference)
//
#include <hip/hip_runtime.h>

// FernBitWord: out[n][j][h][w] = clip((I1 - I2 - th[j] + 0.5)/4, 0, 1)
// where I1/I2 are bilinear taps of zero-padded (PAD=3) channel-1 of x at
// per-bit integer offsets (y,x in [0,5]) + fractional weights.
//
// Design: write-BW-bound (419 MB out). Block = one n, 8 output rows,
// full 160-wide, 32 bits looped. Padded window (14 x 166) staged in LDS.
// Thread = 4-row vertical strip of one column -> row reuse (5 LDS reads/px).
// Weights pre-scaled by +/-0.25 (exact), epilogue is a single clamp.

#define PSTRIDE 168          // LDS floats per window row (>=166)
#define WROWS   14
#define GBITS   32           // bits per block
#define HT      8            // output rows per tile
#define BLK     320          // 5 waves; 160 cols x 2 row-halves

__global__ __launch_bounds__(BLK) void fern_kernel(
    const float* __restrict__ x,
    const float* __restrict__ dx1, const float* __restrict__ dx2,
    const float* __restrict__ dy1, const float* __restrict__ dy2,
    const float* __restrict__ th,
    float* __restrict__ out)
{
    const int rt = blockIdx.x;   // 0..19  row tile
    const int bg = blockIdx.y;   // 0..3   bit group
    const int n  = blockIdx.z;   // 0..31

    __shared__ float  Wbuf[WROWS * PSTRIDE];          // 9408 B
    __shared__ float4 Pw[GBITS][3];                   // weights (pre-scaled), c
    __shared__ int    Po[GBITS][2];                   // o1, o2 window offsets
    __shared__ float  red[BLK / 64];
    __shared__ float  Lsh;

    const int tid = threadIdx.x;

    // ---- L = max |param| (exact: max is order-independent) ----
    float m = 0.f;
    if (tid < 128) {
        m = fmaxf(fmaxf(fabsf(dx1[tid]), fabsf(dx2[tid])),
                  fmaxf(fabsf(dy1[tid]), fabsf(dy2[tid])));
    }
    #pragma unroll
    for (int d = 32; d >= 1; d >>= 1) m = fmaxf(m, __shfl_xor(m, d));
    const int lane = tid & 63, wid = tid >> 6;
    if (lane == 0) red[wid] = m;
    __syncthreads();
    if (tid == 0) {
        float L = red[0];
        #pragma unroll
        for (int i = 1; i < BLK / 64; ++i) L = fmaxf(L, red[i]);
        Lsh = L;
    }
    __syncthreads();
    const float L = Lsh;
    const int shift = 3 - (int)ceilf(L);   // matches astype(int32) trunc

    // ---- per-bit params ----
    if (tid < GBITS) {
        const int j = bg * GBITS + tid;
        const float a1 = dx1[j], a2 = dx2[j], b1 = dy1[j], b2 = dy2[j];
        const float fa1 = floorf(a1), fa2 = floorf(a2);
        const float fb1 = floorf(b1), fb2 = floorf(b2);
        int x1 = (int)(L + fa1) + shift; x1 = min(max(x1, 0), 5);
        int y1 = (int)(L + fb1) + shift; y1 = min(max(y1, 0), 5);
        int x2 = (int)(L + fa2) + shift; x2 = min(max(x2, 0), 5);
        int y2 = (int)(L + fb2) + shift; y2 = min(max(y2, 0), 5);
        const float fx1 = a1 - fa1, fy1 = b1 - fb1;
        const float fx2 = a2 - fa2, fy2 = b2 - fb2;
        // +0.25 for interp1, -0.25 for interp2 (exact power-of-2 scale)
        Pw[tid][0] = make_float4( 0.25f*(1.f-fx1)*(1.f-fy1),  0.25f*fx1*(1.f-fy1),
                                  0.25f*(1.f-fx1)*fy1,        0.25f*fx1*fy1);
        Pw[tid][1] = make_float4(-0.25f*(1.f-fx2)*(1.f-fy2), -0.25f*fx2*(1.f-fy2),
                                 -0.25f*(1.f-fx2)*fy2,       -0.25f*fx2*fy2);
        Pw[tid][2] = make_float4((0.5f - th[j]) * 0.25f, 0.f, 0.f, 0.f);
        Po[tid][0] = y1 * PSTRIDE + x1;
        Po[tid][1] = y2 * PSTRIDE + x2;
    }

    // ---- stage zero-padded window: padded rows h0..h0+13, cols 0..165 ----
    const float* __restrict__ src = x + ((size_t)n * 3 + 1) * 25600;
    const int h0 = rt * HT;
    for (int e = tid; e < WROWS * 166; e += BLK) {
        const int r = e / 166, c = e - r * 166;
        const int sr = h0 + r - 3, sc = c - 3;
        float v = 0.f;
        if ((unsigned)sr < 160u && (unsigned)sc < 160u) v = src[sr * 160 + sc];
        Wbuf[r * PSTRIDE + c] = v;
    }
    __syncthreads();

    // ---- compute: thread = column w, rows rbase..rbase+3 ----
    const int w     = tid % 160;
    const int rb    = tid / 160;      // 0 or 1
    const int rbase = rb * 4;
    const int lbase = rbase * PSTRIDE + w;

    float* __restrict__ outp =
        out + ((size_t)n * 128 + bg * GBITS) * 25600 + (h0 + rbase) * 160 + w;

    #pragma unroll 2
    for (int j = 0; j < GBITS; ++j) {
        const float4 s1 = Pw[j][0];
        const float4 s2 = Pw[j][1];
        const float  c0 = Pw[j][2].x;
        const int o1 = Po[j][0] + lbase;
        const int o2 = Po[j][1] + lbase;

        float acc0 = c0, acc1 = c0, acc2 = c0, acc3 = c0;

        {   // interp 1: rows o1 + k*PSTRIDE, cols +0/+1 (imm offsets)
            float t0 = Wbuf[o1              ], t1 = Wbuf[o1               + 1];
            float u0 = Wbuf[o1 +   PSTRIDE  ], u1 = Wbuf[o1 +   PSTRIDE   + 1];
            acc0 += s1.x*t0 + s1.y*t1 + s1.z*u0 + s1.w*u1;
            t0 = Wbuf[o1 + 2*PSTRIDE]; t1 = Wbuf[o1 + 2*PSTRIDE + 1];
            acc1 += s1.x*u0 + s1.y*u1 + s1.z*t0 + s1.w*t1;
            u0 = Wbuf[o1 + 3*PSTRIDE]; u1 = Wbuf[o1 + 3*PSTRIDE + 1];
            acc2 += s1.x*t0 + s1.y*t1 + s1.z*u0 + s1.w*u1;
            t0 = Wbuf[o1 + 4*PSTRIDE]; t1 = Wbuf[o1 + 4*PSTRIDE + 1];
            acc3 += s1.x*u0 + s1.y*u1 + s1.z*t0 + s1.w*t1;
        }
        {   // interp 2
            float t0 = Wbuf[o2              ], t1 = Wbuf[o2               + 1];
            float u0 = Wbuf[o2 +   PSTRIDE  ], u1 = Wbuf[o2 +   PSTRIDE   + 1];
            acc0 += s2.x*t0 + s2.y*t1 + s2.z*u0 + s2.w*u1;
            t0 = Wbuf[o2 + 2*PSTRIDE]; t1 = Wbuf[o2 + 2*PSTRIDE + 1];
            acc1 += s2.x*u0 + s2.y*u1 + s2.z*t0 + s2.w*t1;
            u0 = Wbuf[o2 + 3*PSTRIDE]; u1 = Wbuf[o2 + 3*PSTRIDE + 1];
            acc2 += s2.x*t0 + s2.y*t1 + s2.z*u0 + s2.w*u1;
            t0 = Wbuf[o2 + 4*PSTRIDE]; t1 = Wbuf[o2 + 4*PSTRIDE + 1];
            acc3 += s2.x*u0 + s2.y*u1 + s2.z*t0 + s2.w*t1;
        }

        // clamp(x,0,1) -> v_med3_f32; stores use imm offsets (640/1280/1920 B)
        outp[  0] = fminf(fmaxf(acc0, 0.f), 1.f);
        outp[160] = fminf(fmaxf(acc1, 0.f), 1.f);
        outp[320] = fminf(fmaxf(acc2, 0.f), 1.f);
        outp[480] = fminf(fmaxf(acc3, 0.f), 1.f);
        outp += 25600;
    }
}

extern "C" void kernel_launch(void* const* d_in, const int* in_sizes, int n_in,
                              void* d_out, int out_size, void* d_ws, size_t ws_size,
                              hipStream_t stream) {
    const float* x   = (const float*)d_in[0];
    const float* dx1 = (const float*)d_in[1];
    const float* dx2 = (const float*)d_in[2];
    const float* dy1 = (const float*)d_in[3];
    const float* dy2 = (const float*)d_in[4];
    const float* th  = (const float*)d_in[5];
    float* out = (float*)d_out;

    dim3 grid(20, 4, 32);   // row-tiles x bit-groups x N
    fern_kernel<<<grid, BLK, 0, stream>>>(x, dx1, dx2, dy1, dy2, th, out);
}